// Round 1
// baseline (1190.107 us; speedup 1.0000x reference)
//
#include <hip/hip_runtime.h>
#include <hip/hip_cooperative_groups.h>

namespace cg = cooperative_groups;

#define C 10
#define CHUNK_ROWS 128
#define CHUNK_FLOATS 1280   // 128 rows * 10
#define CHUNK_F4 320        // float4s per chunk

__device__ __forceinline__ float waveSum(float v) {
#pragma unroll
  for (int o = 32; o > 0; o >>= 1) v += __shfl_down(v, o, 64);
  return v;
}
__device__ __forceinline__ float waveMin(float v) {
#pragma unroll
  for (int o = 32; o > 0; o >>= 1) v = fminf(v, __shfl_down(v, o, 64));
  return v;
}
__device__ __forceinline__ float waveMax(float v) {
#pragma unroll
  for (int o = 32; o > 0; o >>= 1) v = fmaxf(v, __shfl_down(v, o, 64));
  return v;
}
__device__ __forceinline__ unsigned waveMaxU(unsigned v) {
#pragma unroll
  for (int o = 32; o > 0; o >>= 1) {
    unsigned w = (unsigned)__shfl_down((int)v, o, 64);
    v = v > w ? v : w;
  }
  return v;
}

// Single cooperative kernel: phase1 (stream + us/minmax/ce/focal) ->
// grid.sync -> phase2 (histogram, us re-read is L1/L2-hot: same thread,
// same addresses, block never migrates in a cooperative launch) ->
// grid.sync -> phase3 (block 0 finale).
// LDS = 2560 floats (10240 B): phase1 stages ONLY p (log recomputed in row
// phase; trans pipe is idle anyway) -> 16 blocks/CU; launch_bounds(128,8)
// caps VGPR at 64 (prior kernel measured exactly 64 with MORE live state)
// -> 32 waves/CU, 2x the latency hiding of the previous 3-kernel version.
__global__ __launch_bounds__(128, 8) void fused(
    const float4* __restrict__ probs4, const float4* __restrict__ y4,
    float2* __restrict__ us2,
    unsigned* __restrict__ uminInvSlots, unsigned* __restrict__ umaxSlots,
    float* __restrict__ ceSlots, float* __restrict__ focalSlots,
    float* __restrict__ ghist, float* __restrict__ out,
    int nchunks, float invN) {
  __shared__ float lds[2560];  // 10240 B: [wave][p:320 f4] | hist[88][16]+smm
  const int tid = threadIdx.x;
  const int widx = tid >> 6, lane = tid & 63;
  const int gw = blockIdx.x * 2 + widx;   // global wave id
  const int NW = gridDim.x * 2;

  // ---------------- phase 1: streaming ----------------
  {
    float4* const bufP = (float4*)(lds + widx * CHUNK_FLOATS);

    // label0 = argmax of flattened y == label of sample 0 (first max).
    int label0 = 0;
    {
      const float* yf = (const float*)y4;
      float m = yf[0];
#pragma unroll
      for (int c = 1; c < C; ++c) {
        float v = yf[c];
        if (v > m) { m = v; label0 = c; }
      }
    }

    float4 P[5], Y[5];
    auto issue = [&](int c) {
      const float4* gp = probs4 + (size_t)c * CHUNK_F4 + lane;
      const float4* gy = y4 + (size_t)c * CHUNK_F4 + lane;
#pragma unroll
      for (int q = 0; q < 5; ++q) { P[q] = gp[q * 64]; Y[q] = gy[q * 64]; }
    };

    float ceA = 0.f, foA = 0.f;
    float mnA = __uint_as_float(0x7f800000u), mxA = 0.f;

    if (gw < nchunks) issue(gw);
    for (int c = gw; c < nchunks; c += NW) {
      // ---- coalesced elementwise: logs for ce/focal, stage p into LDS.
#pragma unroll
      for (int q = 0; q < 5; ++q) {
        float4 pv = P[q], yv = Y[q];
        float lpx = __logf(fmaxf(pv.x, 1e-10f));
        float lpy = __logf(fmaxf(pv.y, 1e-10f));
        float lpz = __logf(fmaxf(pv.z, 1e-10f));
        float lpw = __logf(fmaxf(pv.w, 1e-10f));
        // lp8 = log(max(p,1e-8)) == max(lp, log(1e-8))
        float tx = yv.x * fmaxf(lpx, -18.420681f);
        float ty = yv.y * fmaxf(lpy, -18.420681f);
        float tz = yv.z * fmaxf(lpz, -18.420681f);
        float tw = yv.w * fmaxf(lpw, -18.420681f);
        ceA -= tx + ty + tz + tw;
        foA -= tx * (1.f - pv.x) + ty * (1.f - pv.y) + tz * (1.f - pv.z) +
               tw * (1.f - pv.w);
        bufP[q * 64 + lane] = pv;
      }

      // ---- prefetch next chunk into dead P/Y regs (stays in flight
      // through the row phase; per-register scoreboard waits).
      if (c + NW < nchunks) issue(c + NW);

      // ---- row phase: lane owns rows 2*lane, 2*lane+1 (5 float4 = 20 elems).
      // Recompute log here (same __logf on same value -> identical bits).
      float u0 = 0.f, u1 = 0.f;
      float m0 = -1.f, m1 = -1.f;  // probs >= 0, so -1 < all
      int am0 = 0, am1 = 0;
#pragma unroll
      for (int q = 0; q < 5; ++q) {
        float4 v = bufP[lane * 5 + q];
        float vv[4] = {v.x, v.y, v.z, v.w};
#pragma unroll
        for (int j = 0; j < 4; ++j) {
          int e = 4 * q + j;  // compile-time after unroll
          float p = vv[j];
          float lp = __logf(fmaxf(p, 1e-10f));
          if (e < 10) {
            u0 -= p * lp;
            if (p > m0) { m0 = p; am0 = e; }      // strict > keeps first max
          } else {
            u1 -= p * lp;
            if (p > m1) { m1 = p; am1 = e - 10; }
          }
        }
      }
      mnA = fminf(mnA, fminf(u0, u1));
      mxA = fmaxf(mxA, fmaxf(u0, u1));

      // pack acc into sign bit (unc >= 0; sign set == inaccurate)
      unsigned s0 = __float_as_uint(u0) | ((am0 == label0) ? 0u : 0x80000000u);
      unsigned s1 = __float_as_uint(u1) | ((am1 == label0) ? 0u : 0x80000000u);
      us2[(size_t)c * 64 + lane] =
          make_float2(__uint_as_float(s0), __uint_as_float(s1));
    }

    float ce = waveSum(ceA), fo = waveSum(foA);
    float mn = waveMin(mnA), mx = waveMax(mxA);
    if (lane == 0) {
      int slot = gw & 63;
      atomicAdd(&ceSlots[slot], ce);
      atomicAdd(&focalSlots[slot], fo);
      atomicMax(&uminInvSlots[slot], ~__float_as_uint(mn));  // min via ~bits
      atomicMax(&umaxSlots[slot], __float_as_uint(mx));
    }
  }
  __threadfence();
  cg::this_grid().sync();

  // ---------------- phase 2: 22-bin x 4-cat histogram ----------------
  {
    float* hist = lds;           // [88][16] = 1408 floats
    float* smm = lds + 1408;     // umin, umax
    for (int i = tid; i < 1408; i += 128) hist[i] = 0.f;
    if (tid < 64) {
      unsigned mnInv = waveMaxU(uminInvSlots[tid]);
      unsigned mxb = waveMaxU(umaxSlots[tid]);
      if (tid == 0) {
        smm[0] = __uint_as_float(~mnInv);
        smm[1] = __uint_as_float(mxb);
      }
    }
    __syncthreads();
    const float umin = smm[0], delta = smm[1] - smm[0];
    float th[21];
#pragma unroll
    for (int k = 0; k < 21; ++k) th[k] = fmaf(0.05f * (float)k, delta, umin);

    const int col = lane & 15;
    for (int c = gw; c < nchunks; c += NW) {
      float2 v = us2[(size_t)c * 64 + lane];  // exactly what THIS thread wrote
      float vv[2] = {v.x, v.y};
#pragma unroll
      for (int q = 0; q < 2; ++q) {
        unsigned b = __float_as_uint(vv[q]);
        int rb = (b >> 31) ? 44 : 0;  // acc rows 0..43, inacc rows 44..87
        float u = __uint_as_float(b & 0x7fffffffu);
        float e = u * 0.4342944819f;  // u / ln(10)
        float lnum = __logf(e * 0.9f);
        float lden = __logf(fmaxf((1.f - e) * 0.1f, 1e-10f));
        float x = fmaxf(lnum - lden, -23.0258509f) * 100.f;
        float s = __builtin_amdgcn_rcpf(1.f + __expf(-x));                   // sigmoid
        float t = 1.f - 2.f * __builtin_amdgcn_rcpf(__expf(2.f * u) + 1.f);  // tanh
        float wc = (1.f - s) * (1.f - t), wu = s * t;
        int j = 0;  // j = #{k: u > th_k}
#pragma unroll
        for (int k = 0; k < 21; ++k) j += (u > th[k]) ? 1 : 0;
        atomicAdd(&hist[(rb + j) * 16 + col], wc);        // ds_add_f32
        atomicAdd(&hist[(rb + 22 + j) * 16 + col], wu);
      }
    }
    __syncthreads();
    // tree-reduce 16 columns per row
#pragma unroll
    for (int st = 8; st >= 1; st >>= 1) {
      for (int idx = tid; idx < 88 * st; idx += 128) {
        int r = idx / st, cc = idx - r * st;
        hist[r * 16 + cc] += hist[r * 16 + cc + st];
      }
      __syncthreads();
    }
    int slot = blockIdx.x & 63;
    for (int r = tid; r < 88; r += 128)
      atomicAdd(&ghist[slot * 88 + r], hist[r * 16]);
  }
  __threadfence();
  cg::this_grid().sync();

  // ---------------- phase 3: block 0 finale ----------------
  if (blockIdx.x == 0) {
    float* hr = lds;        // 88 row sums
    float* scf = lds + 88;  // ce, focal
    if (tid < 64) {
      for (int r = tid; r < 88; r += 64) {
        float s = 0.f;
        for (int q = 0; q < 64; ++q) s += ghist[q * 88 + r];
        hr[r] = s;
      }
    } else {
      int l = tid - 64;
      float ce = waveSum(ceSlots[l]);
      float fo = waveSum(focalSlots[l]);
      if (l == 0) { scf[0] = ce; scf[1] = fo; }
    }
    __syncthreads();
    if (tid == 0) {
      float H0[22], H1[22], H2[22], H3[22];
      float totAU = 0.f, totIU = 0.f;
      for (int j = 0; j < 22; ++j) {
        H0[j] = hr[j]; H1[j] = hr[22 + j]; H2[j] = hr[44 + j]; H3[j] = hr[66 + j];
        totAU += H1[j]; totIU += H3[j];
      }
      float n_ac = 0.f, n_ic = 0.f, n_au = totAU, n_iu = totIU;
      float auc = 0.f, prev = 0.f;
      for (int k = 0; k < 21; ++k) {
        n_ac += H0[k]; n_ic += H2[k];
        n_au -= H1[k]; n_iu -= H3[k];
        float avu = (n_ac + n_iu) / (n_ac + n_au + n_ic + n_iu + 1e-10f);
        if (k > 0) auc += (avu + prev) * 0.5f * 0.05f;
        prev = avu;
      }
      out[0] = -logf(fmaxf(auc, 1e-10f)) + scf[1] * invN;
      out[1] = scf[0] * invN;
    }
  }
}

extern "C" void kernel_launch(void* const* d_in, const int* in_sizes, int n_in,
                              void* d_out, int out_size, void* d_ws, size_t ws_size,
                              hipStream_t stream) {
  const float4* probs4 = (const float4*)d_in[0];
  const float4* y4 = (const float4*)d_in[1];
  float* out = (float*)d_out;
  const int N = in_sizes[0] / C;

  // ws layout (floats): [0,64) uminInv slots, [64,128) umax slots,
  // [128,192) ce slots, [192,256) focal slots, [256,5888) ghist[64][88],
  // [5888, 5888+N) us
  float* wsf = (float*)d_ws;
  unsigned* uminInvSlots = (unsigned*)wsf;
  unsigned* umaxSlots = (unsigned*)(wsf + 64);
  float* ceSlots = wsf + 128;
  float* focalSlots = wsf + 192;
  float* ghist = wsf + 256;
  float2* us2 = (float2*)(wsf + 5888);

  hipMemsetAsync(d_ws, 0, 5888 * sizeof(float), stream);  // accumulators -> 0

  int nchunks = N / CHUNK_ROWS;  // 4194304/128 = 32768
  float invN = 1.0f / (float)N;

  // Cooperative grid: sized from the occupancy query so validation can never
  // fail; expect 16 blocks/CU (LDS 10240 B, VGPR<=64) -> grid 4096, 4
  // chunks/wave. All device loops are grid-stride-safe for any grid.
  static int grid = 0;
  if (grid == 0) {
    int maxb = 0, ncu = 0;
    hipOccupancyMaxActiveBlocksPerMultiprocessor(&maxb, fused, 128, 0);
    hipDeviceGetAttribute(&ncu, hipDeviceAttributeMultiprocessorCount, 0);
    if (maxb < 1) maxb = 1;
    if (ncu < 1) ncu = 256;
    long g = (long)maxb * (long)ncu;
    grid = (int)(g > 4096 ? 4096 : g);
  }

  void* args[] = {(void*)&probs4, (void*)&y4, (void*)&us2,
                  (void*)&uminInvSlots, (void*)&umaxSlots,
                  (void*)&ceSlots, (void*)&focalSlots,
                  (void*)&ghist, (void*)&out, (void*)&nchunks, (void*)&invN};
  hipLaunchCooperativeKernel(fused, dim3(grid), dim3(128), args, 0, stream);
}

// Round 2
// 695.475 us; speedup vs baseline: 1.7112x; 1.7112x over previous
//
#include <hip/hip_runtime.h>
#include <hip/hip_cooperative_groups.h>

namespace cg = cooperative_groups;

#define C 10
#define CHUNK_ROWS 128
#define CHUNK_FLOATS 1280   // 128 rows * 10
#define CHUNK_F4 320        // float4s per chunk

__device__ __forceinline__ float waveSum(float v) {
#pragma unroll
  for (int o = 32; o > 0; o >>= 1) v += __shfl_down(v, o, 64);
  return v;
}
__device__ __forceinline__ float waveMin(float v) {
#pragma unroll
  for (int o = 32; o > 0; o >>= 1) v = fminf(v, __shfl_down(v, o, 64));
  return v;
}
__device__ __forceinline__ float waveMax(float v) {
#pragma unroll
  for (int o = 32; o > 0; o >>= 1) v = fmaxf(v, __shfl_down(v, o, 64));
  return v;
}
__device__ __forceinline__ unsigned waveMaxU(unsigned v) {
#pragma unroll
  for (int o = 32; o > 0; o >>= 1) {
    unsigned w = (unsigned)__shfl_down((int)v, o, 64);
    v = v > w ? v : w;
  }
  return v;
}

// Single cooperative kernel, 3 phases separated by grid.sync().
// LDS = 2560 floats (10240 B) -> 16 blocks/CU possible (16*10240 = 160 KiB).
// launch_bounds(128,4): empirically yields VGPR=64 on this phase-1 body
// (round-0 measured 64, zero spill). (128,8) forced VGPR=32 -> 500 MB of
// scratch traffic (round-1 disaster). At VGPR<=64 the HW still allows
// 8 waves/SIMD, so (128,4) + small LDS reaches 32 waves/CU without
// constraining the allocator below what the prefetch registers need.
// Phase-3 finale walks LDS with running scalars (no H[22] register arrays)
// so it cannot inflate the kernel's static VGPR allocation.
__global__ __launch_bounds__(128, 4) void fused(
    const float4* __restrict__ probs4, const float4* __restrict__ y4,
    float2* __restrict__ us2,
    unsigned* __restrict__ uminInvSlots, unsigned* __restrict__ umaxSlots,
    float* __restrict__ ceSlots, float* __restrict__ focalSlots,
    float* __restrict__ ghist, float* __restrict__ out,
    int nchunks, float invN) {
  __shared__ float lds[2560];  // [wave][p:320 f4] | phase2: hist[88][16]+smm
  const int tid = threadIdx.x;
  const int widx = tid >> 6, lane = tid & 63;
  const int gw = blockIdx.x * 2 + widx;   // global wave id
  const int NW = gridDim.x * 2;

  // ---------------- phase 1: streaming ----------------
  {
    float4* const bufP = (float4*)(lds + widx * CHUNK_FLOATS);

    // label0 = argmax of flattened y == label of sample 0 (first max).
    int label0 = 0;
    {
      const float* yf = (const float*)y4;
      float m = yf[0];
#pragma unroll
      for (int c = 1; c < C; ++c) {
        float v = yf[c];
        if (v > m) { m = v; label0 = c; }
      }
    }

    float4 P[5], Y[5];
    auto issue = [&](int c) {
      const float4* gp = probs4 + (size_t)c * CHUNK_F4 + lane;
      const float4* gy = y4 + (size_t)c * CHUNK_F4 + lane;
#pragma unroll
      for (int q = 0; q < 5; ++q) { P[q] = gp[q * 64]; Y[q] = gy[q * 64]; }
    };

    float ceA = 0.f, foA = 0.f;
    float mnA = __uint_as_float(0x7f800000u), mxA = 0.f;

    if (gw < nchunks) issue(gw);
    for (int c = gw; c < nchunks; c += NW) {
      // ---- coalesced elementwise: logs for ce/focal, stage p into LDS.
#pragma unroll
      for (int q = 0; q < 5; ++q) {
        float4 pv = P[q], yv = Y[q];
        float lpx = __logf(fmaxf(pv.x, 1e-10f));
        float lpy = __logf(fmaxf(pv.y, 1e-10f));
        float lpz = __logf(fmaxf(pv.z, 1e-10f));
        float lpw = __logf(fmaxf(pv.w, 1e-10f));
        // lp8 = log(max(p,1e-8)) == max(lp, log(1e-8))
        float tx = yv.x * fmaxf(lpx, -18.420681f);
        float ty = yv.y * fmaxf(lpy, -18.420681f);
        float tz = yv.z * fmaxf(lpz, -18.420681f);
        float tw = yv.w * fmaxf(lpw, -18.420681f);
        ceA -= tx + ty + tz + tw;
        foA -= tx * (1.f - pv.x) + ty * (1.f - pv.y) + tz * (1.f - pv.z) +
               tw * (1.f - pv.w);
        bufP[q * 64 + lane] = pv;
      }

      // ---- prefetch next chunk into dead P/Y regs (stays in flight
      // through the row phase; per-register scoreboard waits).
      if (c + NW < nchunks) issue(c + NW);

      // ---- row phase: lane owns rows 2*lane, 2*lane+1 (5 float4 = 20 elems).
      float u0 = 0.f, u1 = 0.f;
      float m0 = -1.f, m1 = -1.f;  // probs >= 0, so -1 < all
      int am0 = 0, am1 = 0;
#pragma unroll
      for (int q = 0; q < 5; ++q) {
        float4 v = bufP[lane * 5 + q];
        float vv[4] = {v.x, v.y, v.z, v.w};
#pragma unroll
        for (int j = 0; j < 4; ++j) {
          int e = 4 * q + j;  // compile-time after unroll
          float p = vv[j];
          float lp = __logf(fmaxf(p, 1e-10f));
          if (e < 10) {
            u0 -= p * lp;
            if (p > m0) { m0 = p; am0 = e; }      // strict > keeps first max
          } else {
            u1 -= p * lp;
            if (p > m1) { m1 = p; am1 = e - 10; }
          }
        }
      }
      mnA = fminf(mnA, fminf(u0, u1));
      mxA = fmaxf(mxA, fmaxf(u0, u1));

      // pack acc into sign bit (unc >= 0; sign set == inaccurate)
      unsigned s0 = __float_as_uint(u0) | ((am0 == label0) ? 0u : 0x80000000u);
      unsigned s1 = __float_as_uint(u1) | ((am1 == label0) ? 0u : 0x80000000u);
      us2[(size_t)c * 64 + lane] =
          make_float2(__uint_as_float(s0), __uint_as_float(s1));
    }

    float ce = waveSum(ceA), fo = waveSum(foA);
    float mn = waveMin(mnA), mx = waveMax(mxA);
    if (lane == 0) {
      int slot = gw & 63;
      atomicAdd(&ceSlots[slot], ce);
      atomicAdd(&focalSlots[slot], fo);
      atomicMax(&uminInvSlots[slot], ~__float_as_uint(mn));  // min via ~bits
      atomicMax(&umaxSlots[slot], __float_as_uint(mx));
    }
  }
  __threadfence();
  cg::this_grid().sync();

  // ---------------- phase 2: 22-bin x 4-cat histogram ----------------
  {
    float* hist = lds;           // [88][16] = 1408 floats
    float* smm = lds + 1408;     // umin, umax
    for (int i = tid; i < 1408; i += 128) hist[i] = 0.f;
    if (tid < 64) {
      unsigned mnInv = waveMaxU(uminInvSlots[tid]);
      unsigned mxb = waveMaxU(umaxSlots[tid]);
      if (tid == 0) {
        smm[0] = __uint_as_float(~mnInv);
        smm[1] = __uint_as_float(mxb);
      }
    }
    __syncthreads();
    const float umin = smm[0], delta = smm[1] - smm[0];
    float th[21];
#pragma unroll
    for (int k = 0; k < 21; ++k) th[k] = fmaf(0.05f * (float)k, delta, umin);

    const int col = lane & 15;
    for (int c = gw; c < nchunks; c += NW) {
      float2 v = us2[(size_t)c * 64 + lane];  // exactly what THIS thread wrote
      float vv[2] = {v.x, v.y};
#pragma unroll
      for (int q = 0; q < 2; ++q) {
        unsigned b = __float_as_uint(vv[q]);
        int rb = (b >> 31) ? 44 : 0;  // acc rows 0..43, inacc rows 44..87
        float u = __uint_as_float(b & 0x7fffffffu);
        float e = u * 0.4342944819f;  // u / ln(10)
        float lnum = __logf(e * 0.9f);
        float lden = __logf(fmaxf((1.f - e) * 0.1f, 1e-10f));
        float x = fmaxf(lnum - lden, -23.0258509f) * 100.f;
        float s = __builtin_amdgcn_rcpf(1.f + __expf(-x));                   // sigmoid
        float t = 1.f - 2.f * __builtin_amdgcn_rcpf(__expf(2.f * u) + 1.f);  // tanh
        float wc = (1.f - s) * (1.f - t), wu = s * t;
        int j = 0;  // j = #{k: u > th_k}
#pragma unroll
        for (int k = 0; k < 21; ++k) j += (u > th[k]) ? 1 : 0;
        atomicAdd(&hist[(rb + j) * 16 + col], wc);        // ds_add_f32
        atomicAdd(&hist[(rb + 22 + j) * 16 + col], wu);
      }
    }
    __syncthreads();
    // tree-reduce 16 columns per row
#pragma unroll
    for (int st = 8; st >= 1; st >>= 1) {
      for (int idx = tid; idx < 88 * st; idx += 128) {
        int r = idx / st, cc = idx - r * st;
        hist[r * 16 + cc] += hist[r * 16 + cc + st];
      }
      __syncthreads();
    }
    int slot = blockIdx.x & 63;
    for (int r = tid; r < 88; r += 128)
      atomicAdd(&ghist[slot * 88 + r], hist[r * 16]);
  }
  __threadfence();
  cg::this_grid().sync();

  // ---------------- phase 3: block 0 finale (LDS-walking, low-VGPR) --------
  if (blockIdx.x == 0) {
    float* hr = lds;         // 88 row sums
    float* scf = lds + 96;   // ce, focal
    if (tid < 64) {
      for (int r = tid; r < 88; r += 64) {
        float s = 0.f;
        for (int q = 0; q < 64; ++q) s += ghist[q * 88 + r];
        hr[r] = s;
      }
    } else {
      int l = tid - 64;
      float ce = waveSum(ceSlots[l]);
      float fo = waveSum(focalSlots[l]);
      if (l == 0) { scf[0] = ce; scf[1] = fo; }
    }
    __syncthreads();
    if (tid == 0) {
      // Running sums read straight from LDS -> ~8 live registers, no arrays.
      float totAU = 0.f, totIU = 0.f;
      for (int j = 0; j < 22; ++j) { totAU += hr[22 + j]; totIU += hr[66 + j]; }
      float n_ac = 0.f, n_ic = 0.f, n_au = totAU, n_iu = totIU;
      float auc = 0.f, prev = 0.f;
      for (int k = 0; k < 21; ++k) {
        n_ac += hr[k]; n_ic += hr[44 + k];
        n_au -= hr[22 + k]; n_iu -= hr[66 + k];
        float avu = (n_ac + n_iu) / (n_ac + n_au + n_ic + n_iu + 1e-10f);
        if (k > 0) auc += (avu + prev) * 0.5f * 0.05f;
        prev = avu;
      }
      out[0] = -logf(fmaxf(auc, 1e-10f)) + scf[1] * invN;
      out[1] = scf[0] * invN;
    }
  }
}

extern "C" void kernel_launch(void* const* d_in, const int* in_sizes, int n_in,
                              void* d_out, int out_size, void* d_ws, size_t ws_size,
                              hipStream_t stream) {
  const float4* probs4 = (const float4*)d_in[0];
  const float4* y4 = (const float4*)d_in[1];
  float* out = (float*)d_out;
  const int N = in_sizes[0] / C;

  // ws layout (floats): [0,64) uminInv slots, [64,128) umax slots,
  // [128,192) ce slots, [192,256) focal slots, [256,5888) ghist[64][88],
  // [5888, 5888+N) us
  float* wsf = (float*)d_ws;
  unsigned* uminInvSlots = (unsigned*)wsf;
  unsigned* umaxSlots = (unsigned*)(wsf + 64);
  float* ceSlots = wsf + 128;
  float* focalSlots = wsf + 192;
  float* ghist = wsf + 256;
  float2* us2 = (float2*)(wsf + 5888);

  hipMemsetAsync(d_ws, 0, 5888 * sizeof(float), stream);  // accumulators -> 0

  int nchunks = N / CHUNK_ROWS;  // 4194304/128 = 32768
  float invN = 1.0f / (float)N;

  // Cooperative grid sized from the occupancy query so validation can never
  // fail; expect 16 blocks/CU (LDS 10240 B, VGPR<=64) -> grid 4096, 4
  // chunks/wave. All device loops are grid-stride-safe for any grid.
  static int grid = 0;
  if (grid == 0) {
    int maxb = 0, ncu = 0;
    hipOccupancyMaxActiveBlocksPerMultiprocessor(&maxb, fused, 128, 0);
    hipDeviceGetAttribute(&ncu, hipDeviceAttributeMultiprocessorCount, 0);
    if (maxb < 1) maxb = 1;
    if (ncu < 1) ncu = 256;
    long g = (long)maxb * (long)ncu;
    grid = (int)(g > 4096 ? 4096 : g);
  }

  void* args[] = {(void*)&probs4, (void*)&y4, (void*)&us2,
                  (void*)&uminInvSlots, (void*)&umaxSlots,
                  (void*)&ceSlots, (void*)&focalSlots,
                  (void*)&ghist, (void*)&out, (void*)&nchunks, (void*)&invN};
  hipLaunchCooperativeKernel(fused, dim3(grid), dim3(128), args, 0, stream);
}

// Round 3
// 513.164 us; speedup vs baseline: 2.3192x; 1.3553x over previous
//
#include <hip/hip_runtime.h>

#define C 10
#define CHUNK_ROWS 128
#define CHUNK_FLOATS 1280   // 128 rows * 10
#define CHUNK_F4 320        // float4s per chunk

__device__ __forceinline__ float waveSum(float v) {
#pragma unroll
  for (int o = 32; o > 0; o >>= 1) v += __shfl_down(v, o, 64);
  return v;
}
__device__ __forceinline__ float waveMin(float v) {
#pragma unroll
  for (int o = 32; o > 0; o >>= 1) v = fminf(v, __shfl_down(v, o, 64));
  return v;
}
__device__ __forceinline__ float waveMax(float v) {
#pragma unroll
  for (int o = 32; o > 0; o >>= 1) v = fmaxf(v, __shfl_down(v, o, 64));
  return v;
}
__device__ __forceinline__ unsigned waveMaxU(unsigned v) {
#pragma unroll
  for (int o = 32; o > 0; o >>= 1) {
    unsigned w = (unsigned)__shfl_down((int)v, o, 64);
    v = v > w ? v : w;
  }
  return v;
}

// ---------------- pass 1: register-pipelined streaming (NON-cooperative;
// cooperative launch measured 6x lower streaming BW in rounds 1-2).
// LDS halved vs round-0: stage ONLY p (10240 B/block), recompute log in the
// row phase (trans pipe ~idle; ~1 us device-wide). 16 blocks/CU now fit
// (16*10240 = 160 KiB exactly); grid 4096 = one full resident generation,
// 4 chunks/wave. launch_bounds(128,4): round-0 measured VGPR=64 zero-spill
// on this body; (128,8) forced 32 VGPR -> 500 MB scratch disaster (round 1).
__global__ __launch_bounds__(128, 4) void pass1(
    const float4* __restrict__ probs4, const float4* __restrict__ y4,
    float2* __restrict__ us2,
    unsigned* __restrict__ uminInvSlots, unsigned* __restrict__ umaxSlots,
    float* __restrict__ ceSlots, float* __restrict__ focalSlots,
    int nchunks) {
  __shared__ float lds[2 * CHUNK_FLOATS];  // [wave][p: 320 float4] = 10240 B
  const int widx = threadIdx.x >> 6, lane = threadIdx.x & 63;
  float4* const bufP = (float4*)(lds + widx * CHUNK_FLOATS);

  const int gw = blockIdx.x * 2 + widx;  // global wave id
  const int NW = gridDim.x * 2;

  // label0 = argmax of flattened y == label of sample 0 (first max). L2-hot.
  int label0 = 0;
  {
    const float* yf = (const float*)y4;
    float m = yf[0];
#pragma unroll
    for (int c = 1; c < C; ++c) {
      float v = yf[c];
      if (v > m) { m = v; label0 = c; }
    }
  }

  float4 P[5], Y[5];
  auto issue = [&](int c) {
    const float4* gp = probs4 + (size_t)c * CHUNK_F4 + lane;
    const float4* gy = y4 + (size_t)c * CHUNK_F4 + lane;
#pragma unroll
    for (int q = 0; q < 5; ++q) { P[q] = gp[q * 64]; Y[q] = gy[q * 64]; }
  };

  float ceA = 0.f, foA = 0.f;
  float mnA = __uint_as_float(0x7f800000u), mxA = 0.f;

  if (gw < nchunks) issue(gw);
  for (int c = gw; c < nchunks; c += NW) {
    // ---- elementwise phase (coalesced): logs for ce/focal, stage p to LDS.
#pragma unroll
    for (int q = 0; q < 5; ++q) {
      float4 pv = P[q], yv = Y[q];
      float lpx = __logf(fmaxf(pv.x, 1e-10f));
      float lpy = __logf(fmaxf(pv.y, 1e-10f));
      float lpz = __logf(fmaxf(pv.z, 1e-10f));
      float lpw = __logf(fmaxf(pv.w, 1e-10f));
      // lp8 = log(max(p,1e-8)) == max(lp, log(1e-8))
      float tx = yv.x * fmaxf(lpx, -18.420681f);
      float ty = yv.y * fmaxf(lpy, -18.420681f);
      float tz = yv.z * fmaxf(lpz, -18.420681f);
      float tw = yv.w * fmaxf(lpw, -18.420681f);
      ceA -= tx + ty + tz + tw;
      foA -= tx * (1.f - pv.x) + ty * (1.f - pv.y) + tz * (1.f - pv.z) +
             tw * (1.f - pv.w);
      bufP[q * 64 + lane] = pv;
    }

    // ---- prefetch next chunk into dead P/Y regs (stays in flight through
    // the row phase; per-register scoreboard waits).
    if (c + NW < nchunks) issue(c + NW);

    // ---- row phase: lane owns rows 2*lane, 2*lane+1 (5 float4 = 20 elems).
    // Recompute log (same __logf on same value -> identical bits).
    float u0 = 0.f, u1 = 0.f;
    float m0 = -1.f, m1 = -1.f;
    int am0 = 0, am1 = 0;
#pragma unroll
    for (int q = 0; q < 5; ++q) {
      float4 v = bufP[lane * 5 + q];
      float vv[4] = {v.x, v.y, v.z, v.w};
#pragma unroll
      for (int j = 0; j < 4; ++j) {
        int e = 4 * q + j;  // compile-time after unroll
        float p = vv[j];
        float lp = __logf(fmaxf(p, 1e-10f));
        if (e < 10) {
          u0 -= p * lp;
          if (p > m0) { m0 = p; am0 = e; }      // strict > keeps first max
        } else {
          u1 -= p * lp;
          if (p > m1) { m1 = p; am1 = e - 10; }
        }
      }
    }
    mnA = fminf(mnA, fminf(u0, u1));
    mxA = fmaxf(mxA, fmaxf(u0, u1));

    // pack acc into sign bit (unc >= 0; sign set == inaccurate)
    unsigned s0 = __float_as_uint(u0) | ((am0 == label0) ? 0u : 0x80000000u);
    unsigned s1 = __float_as_uint(u1) | ((am1 == label0) ? 0u : 0x80000000u);
    us2[(size_t)c * 64 + lane] =
        make_float2(__uint_as_float(s0), __uint_as_float(s1));
  }

  // per-wave reduce + spread-slot atomics (no LDS scratch needed).
  float ce = waveSum(ceA), fo = waveSum(foA);
  float mn = waveMin(mnA), mx = waveMax(mxA);
  if (lane == 0) {
    int slot = gw & 63;
    atomicAdd(&ceSlots[slot], ce);
    atomicAdd(&focalSlots[slot], fo);
    atomicMax(&uminInvSlots[slot], ~__float_as_uint(mn));  // min via ~bits
    atomicMax(&umaxSlots[slot], __float_as_uint(mx));
  }
}

// ---------------- pass 2 + finale: histogram with last-block-done reduction.
// Non-cooperative: blocks bump a device counter after flushing ghist; the
// last block re-reads ghist with AGENT-scope atomic loads (cross-XCD safe)
// and emits the outputs. Saves the pass3 launch + drain.
__global__ __launch_bounds__(256, 4) void pass2f(
    const float4* __restrict__ us4, int n4,
    const unsigned* __restrict__ uminInvSlots, const unsigned* __restrict__ umaxSlots,
    const float* __restrict__ ceSlots, const float* __restrict__ focalSlots,
    float* __restrict__ ghist, unsigned* __restrict__ doneCount,
    float* __restrict__ out, float invN) {
  __shared__ float hist[88 * 64];  // [row][lane], 22528 B
  __shared__ float smm[2];
  __shared__ unsigned isLast;
  const int tid = threadIdx.x, lane = tid & 63;
  for (int i = tid; i < 88 * 64; i += 256) hist[i] = 0.f;
  if (tid < 64) {
    unsigned mnInv = waveMaxU(uminInvSlots[tid]);
    unsigned mxb = waveMaxU(umaxSlots[tid]);
    if (tid == 0) { smm[0] = __uint_as_float(~mnInv); smm[1] = __uint_as_float(mxb); }
  }
  __syncthreads();
  const float umin = smm[0], delta = smm[1] - smm[0];
  float th[21];
#pragma unroll
  for (int k = 0; k < 21; ++k) th[k] = fmaf(0.05f * (float)k, delta, umin);

  const int stride = gridDim.x * 256;
  for (int i = blockIdx.x * 256 + tid; i < n4; i += stride) {
    float4 v = us4[i];
    float vv[4] = {v.x, v.y, v.z, v.w};
#pragma unroll
    for (int q = 0; q < 4; ++q) {
      unsigned b = __float_as_uint(vv[q]);
      int rb = (b >> 31) ? 44 : 0;  // acc rows 0..43, inacc rows 44..87
      float u = __uint_as_float(b & 0x7fffffffu);
      float e = u * 0.4342944819f;  // u / ln(10)
      float lnum = __logf(e * 0.9f);
      float lden = __logf(fmaxf((1.f - e) * 0.1f, 1e-10f));
      float x = fmaxf(lnum - lden, -23.0258509f) * 100.f;
      float s = __builtin_amdgcn_rcpf(1.f + __expf(-x));                   // sigmoid
      float t = 1.f - 2.f * __builtin_amdgcn_rcpf(__expf(2.f * u) + 1.f);  // tanh
      float wc = (1.f - s) * (1.f - t), wu = s * t;
      int j = 0;  // j = #{k: u > th_k}; le[k] <=> k >= j
#pragma unroll
      for (int k = 0; k < 21; ++k) j += (u > th[k]) ? 1 : 0;
      atomicAdd(&hist[(rb + j) * 64 + lane], wc);        // ds_add_f32
      atomicAdd(&hist[(rb + 22 + j) * 64 + lane], wu);
    }
  }
  __syncthreads();
  // tree-reduce 64 columns per row
#pragma unroll
  for (int st = 32; st >= 1; st >>= 1) {
    for (int idx = tid; idx < 88 * st; idx += 256) {
      int r = idx / st, c = idx - r * st;
      hist[r * 64 + c] += hist[r * 64 + c + st];
    }
    __syncthreads();
  }
  int slot = blockIdx.x & 63;
  for (int r = tid; r < 88; r += 256)
    atomicAdd(&ghist[slot * 88 + r], hist[r * 64]);

  // ---- last-block-done: fence, bump counter, last block runs the finale.
  __threadfence();
  if (tid == 0) isLast = (atomicAdd(doneCount, 1u) == (unsigned)gridDim.x - 1u);
  __syncthreads();
  if (!isLast) return;
  __threadfence();  // acquire side before reading other blocks' ghist

  // finale: reuse hist LDS as hr[88] + scf[2]. Agent-scope atomic loads so
  // cross-XCD L2 writes are observed.
  float* hr = hist;
  float* scf = hist + 96;
  if (tid < 88) {
    float s = 0.f;
    for (int q = 0; q < 64; ++q)
      s += __hip_atomic_load(&ghist[q * 88 + tid], __ATOMIC_RELAXED,
                             __HIP_MEMORY_SCOPE_AGENT);
    hr[tid] = s;
  }
  if (tid >= 128 && tid < 192) {
    int l = tid - 128;
    float ce = waveSum(ceSlots[l]);   // written by pass1 (kernel boundary)
    float fo = waveSum(focalSlots[l]);
    if (l == 0) { scf[0] = ce; scf[1] = fo; }
  }
  __syncthreads();
  if (tid == 0) {
    float totAU = 0.f, totIU = 0.f;
    for (int j = 0; j < 22; ++j) { totAU += hr[22 + j]; totIU += hr[66 + j]; }
    float n_ac = 0.f, n_ic = 0.f, n_au = totAU, n_iu = totIU;
    float auc = 0.f, prev = 0.f;
    for (int k = 0; k < 21; ++k) {
      n_ac += hr[k]; n_ic += hr[44 + k];
      n_au -= hr[22 + k]; n_iu -= hr[66 + k];
      float avu = (n_ac + n_iu) / (n_ac + n_au + n_ic + n_iu + 1e-10f);
      if (k > 0) auc += (avu + prev) * 0.5f * 0.05f;
      prev = avu;
    }
    out[0] = -logf(fmaxf(auc, 1e-10f)) + scf[1] * invN;
    out[1] = scf[0] * invN;
  }
}

extern "C" void kernel_launch(void* const* d_in, const int* in_sizes, int n_in,
                              void* d_out, int out_size, void* d_ws, size_t ws_size,
                              hipStream_t stream) {
  const float* probs = (const float*)d_in[0];
  const float* y = (const float*)d_in[1];
  float* out = (float*)d_out;
  const int N = in_sizes[0] / C;

  // ws layout (floats): [0,64) uminInv slots, [64,128) umax slots,
  // [128,192) ce slots, [192,256) focal slots, [256] doneCount,
  // [260, 260+5632) ghist[64][88], [5892, 5892+N) us (23568 B, 16B-aligned)
  float* wsf = (float*)d_ws;
  unsigned* uminInvSlots = (unsigned*)wsf;
  unsigned* umaxSlots = (unsigned*)(wsf + 64);
  float* ceSlots = wsf + 128;
  float* focalSlots = wsf + 192;
  unsigned* doneCount = (unsigned*)(wsf + 256);
  float* ghist = wsf + 260;
  float* us = wsf + 5892;

  hipMemsetAsync(d_ws, 0, 5892 * sizeof(float), stream);  // accumulators -> 0

  const int nchunks = N / CHUNK_ROWS;  // 4194304/128 = 32768
  float invN = 1.0f / (float)N;

  // grid 4096 = 16 blocks/CU (LDS 10240 B) -> one fully-resident generation,
  // 4 chunks/wave.
  pass1<<<4096, 128, 0, stream>>>((const float4*)probs, (const float4*)y,
                                  (float2*)us, uminInvSlots, umaxSlots,
                                  ceSlots, focalSlots, nchunks);
  pass2f<<<2048, 256, 0, stream>>>((const float4*)us, N / 4, uminInvSlots,
                                   umaxSlots, ceSlots, focalSlots, ghist,
                                   doneCount, out, invN);
}

// Round 4
// 379.444 us; speedup vs baseline: 3.1364x; 1.3524x over previous
//
#include <hip/hip_runtime.h>

#define C 10
#define CHUNK_ROWS 128
#define CHUNK_FLOATS 1280   // 128 rows * 10
#define CHUNK_F4 320        // float4s per chunk

typedef float f4_t __attribute__((ext_vector_type(4)));
typedef float f2_t __attribute__((ext_vector_type(2)));

__device__ __forceinline__ float waveSum(float v) {
#pragma unroll
  for (int o = 32; o > 0; o >>= 1) v += __shfl_down(v, o, 64);
  return v;
}
__device__ __forceinline__ float waveMin(float v) {
#pragma unroll
  for (int o = 32; o > 0; o >>= 1) v = fminf(v, __shfl_down(v, o, 64));
  return v;
}
__device__ __forceinline__ float waveMax(float v) {
#pragma unroll
  for (int o = 32; o > 0; o >>= 1) v = fmaxf(v, __shfl_down(v, o, 64));
  return v;
}
__device__ __forceinline__ unsigned waveMaxU(unsigned v) {
#pragma unroll
  for (int o = 32; o > 0; o >>= 1) {
    unsigned w = (unsigned)__shfl_down((int)v, o, 64);
    v = v > w ? v : w;
  }
  return v;
}

// ---------------- pass 1: register-pipelined streaming, NON-cooperative.
// NT loads on the once-streamed inputs; NT stores on us so the lines get
// evicted/written back early instead of sitting DIRTY in remote XCD L2s
// (theory: pass2's slow us read = cross-XCD dirty-line probes).
// LDS 10240 B/block (p only; log recomputed in row phase). grid 4096.
__global__ __launch_bounds__(128, 4) void pass1(
    const float4* __restrict__ probs4, const float4* __restrict__ y4,
    float2* __restrict__ us2,
    unsigned* __restrict__ uminInvSlots, unsigned* __restrict__ umaxSlots,
    float* __restrict__ ceSlots, float* __restrict__ focalSlots,
    int nchunks) {
  __shared__ float lds[2 * CHUNK_FLOATS];  // [wave][p: 320 f4] = 10240 B
  const int widx = threadIdx.x >> 6, lane = threadIdx.x & 63;
  f4_t* const bufP = (f4_t*)(lds + widx * CHUNK_FLOATS);

  const int gw = blockIdx.x * 2 + widx;  // global wave id
  const int NW = gridDim.x * 2;

  // label0 = argmax of flattened y == label of sample 0 (first max). L2-hot.
  int label0 = 0;
  {
    const float* yf = (const float*)y4;
    float m = yf[0];
#pragma unroll
    for (int c = 1; c < C; ++c) {
      float v = yf[c];
      if (v > m) { m = v; label0 = c; }
    }
  }

  f4_t P[5], Y[5];
  auto issue = [&](int c) {
    const f4_t* gp = (const f4_t*)probs4 + (size_t)c * CHUNK_F4 + lane;
    const f4_t* gy = (const f4_t*)y4 + (size_t)c * CHUNK_F4 + lane;
#pragma unroll
    for (int q = 0; q < 5; ++q) {
      P[q] = __builtin_nontemporal_load(gp + q * 64);
      Y[q] = __builtin_nontemporal_load(gy + q * 64);
    }
  };

  float ceA = 0.f, foA = 0.f;
  float mnA = __uint_as_float(0x7f800000u), mxA = 0.f;

  if (gw < nchunks) issue(gw);
  for (int c = gw; c < nchunks; c += NW) {
    // ---- elementwise phase (coalesced): logs for ce/focal, stage p to LDS.
#pragma unroll
    for (int q = 0; q < 5; ++q) {
      f4_t pv = P[q], yv = Y[q];
      float lpx = __logf(fmaxf(pv.x, 1e-10f));
      float lpy = __logf(fmaxf(pv.y, 1e-10f));
      float lpz = __logf(fmaxf(pv.z, 1e-10f));
      float lpw = __logf(fmaxf(pv.w, 1e-10f));
      // lp8 = log(max(p,1e-8)) == max(lp, log(1e-8))
      float tx = yv.x * fmaxf(lpx, -18.420681f);
      float ty = yv.y * fmaxf(lpy, -18.420681f);
      float tz = yv.z * fmaxf(lpz, -18.420681f);
      float tw = yv.w * fmaxf(lpw, -18.420681f);
      ceA -= tx + ty + tz + tw;
      foA -= tx * (1.f - pv.x) + ty * (1.f - pv.y) + tz * (1.f - pv.z) +
             tw * (1.f - pv.w);
      bufP[q * 64 + lane] = pv;
    }

    // ---- prefetch next chunk into dead P/Y regs (stays in flight through
    // the row phase; per-register scoreboard waits).
    if (c + NW < nchunks) issue(c + NW);

    // ---- row phase: lane owns rows 2*lane, 2*lane+1 (5 float4 = 20 elems).
    float u0 = 0.f, u1 = 0.f;
    float m0 = -1.f, m1 = -1.f;
    int am0 = 0, am1 = 0;
#pragma unroll
    for (int q = 0; q < 5; ++q) {
      f4_t v = bufP[lane * 5 + q];
      float vv[4] = {v.x, v.y, v.z, v.w};
#pragma unroll
      for (int j = 0; j < 4; ++j) {
        int e = 4 * q + j;  // compile-time after unroll
        float p = vv[j];
        float lp = __logf(fmaxf(p, 1e-10f));
        if (e < 10) {
          u0 -= p * lp;
          if (p > m0) { m0 = p; am0 = e; }      // strict > keeps first max
        } else {
          u1 -= p * lp;
          if (p > m1) { m1 = p; am1 = e - 10; }
        }
      }
    }
    mnA = fminf(mnA, fminf(u0, u1));
    mxA = fmaxf(mxA, fmaxf(u0, u1));

    // pack acc into sign bit (unc >= 0; sign set == inaccurate)
    unsigned s0 = __float_as_uint(u0) | ((am0 == label0) ? 0u : 0x80000000u);
    unsigned s1 = __float_as_uint(u1) | ((am1 == label0) ? 0u : 0x80000000u);
    f2_t o;
    o.x = __uint_as_float(s0);
    o.y = __uint_as_float(s1);
    __builtin_nontemporal_store(o, (f2_t*)&us2[(size_t)c * 64 + lane]);
  }

  // per-wave reduce + spread-slot atomics.
  float ce = waveSum(ceA), fo = waveSum(foA);
  float mn = waveMin(mnA), mx = waveMax(mxA);
  if (lane == 0) {
    int slot = gw & 63;
    atomicAdd(&ceSlots[slot], ce);
    atomicAdd(&focalSlots[slot], fo);
    atomicMax(&uminInvSlots[slot], ~__float_as_uint(mn));  // min via ~bits
    atomicMax(&umaxSlots[slot], __float_as_uint(mx));
  }
}

// ---------------- pass 2: 22-bin x 4-category histogram (round-0 structure:
// grid 1024 = one resident generation; NO done-counter, NO fused finale —
// both were round-3 suspects: same-address cross-XCD atomics + serial
// agent-scope loads). NT loads on us (read exactly once).
__global__ __launch_bounds__(256, 4) void pass2(
    const float4* __restrict__ us4, int n4,
    const unsigned* __restrict__ uminInvSlots, const unsigned* __restrict__ umaxSlots,
    float* __restrict__ ghist) {
  __shared__ float hist[88 * 64];  // [row][lane], 22528 B
  __shared__ float smm[2];
  const int tid = threadIdx.x, lane = tid & 63;
  for (int i = tid; i < 88 * 64; i += 256) hist[i] = 0.f;
  if (tid < 64) {
    unsigned mnInv = waveMaxU(uminInvSlots[tid]);
    unsigned mxb = waveMaxU(umaxSlots[tid]);
    if (tid == 0) { smm[0] = __uint_as_float(~mnInv); smm[1] = __uint_as_float(mxb); }
  }
  __syncthreads();
  const float umin = smm[0], delta = smm[1] - smm[0];
  float th[21];
#pragma unroll
  for (int k = 0; k < 21; ++k) th[k] = fmaf(0.05f * (float)k, delta, umin);

  const int stride = gridDim.x * 256;
  for (int i = blockIdx.x * 256 + tid; i < n4; i += stride) {
    f4_t v = __builtin_nontemporal_load((const f4_t*)us4 + i);
    float vv[4] = {v.x, v.y, v.z, v.w};
#pragma unroll
    for (int q = 0; q < 4; ++q) {
      unsigned b = __float_as_uint(vv[q]);
      int rb = (b >> 31) ? 44 : 0;  // acc rows 0..43, inacc rows 44..87
      float u = __uint_as_float(b & 0x7fffffffu);
      float e = u * 0.4342944819f;  // u / ln(10)
      float lnum = __logf(e * 0.9f);
      float lden = __logf(fmaxf((1.f - e) * 0.1f, 1e-10f));
      float x = fmaxf(lnum - lden, -23.0258509f) * 100.f;
      float s = __builtin_amdgcn_rcpf(1.f + __expf(-x));                   // sigmoid
      float t = 1.f - 2.f * __builtin_amdgcn_rcpf(__expf(2.f * u) + 1.f);  // tanh
      float wc = (1.f - s) * (1.f - t), wu = s * t;
      int j = 0;  // j = #{k: u > th_k}; le[k] <=> k >= j
#pragma unroll
      for (int k = 0; k < 21; ++k) j += (u > th[k]) ? 1 : 0;
      atomicAdd(&hist[(rb + j) * 64 + lane], wc);        // ds_add_f32
      atomicAdd(&hist[(rb + 22 + j) * 64 + lane], wu);
    }
  }
  __syncthreads();
  // tree-reduce 64 columns per row
#pragma unroll
  for (int st = 32; st >= 1; st >>= 1) {
    for (int idx = tid; idx < 88 * st; idx += 256) {
      int r = idx / st, c = idx - r * st;
      hist[r * 64 + c] += hist[r * 64 + c + st];
    }
    __syncthreads();
  }
  int slot = blockIdx.x & 63;
  for (int r = tid; r < 88; r += 256)
    atomicAdd(&ghist[slot * 88 + r], hist[r * 64]);
}

// ---------------- pass 3: reduce 64 slot-copies + scalar slots, emit outputs
__global__ __launch_bounds__(256) void pass3(
    const float* __restrict__ ghist,
    const float* __restrict__ ceSlots, const float* __restrict__ focalSlots,
    float* __restrict__ out, float invN) {
  __shared__ float hr[96];
  __shared__ float scf[2];
  int tid = threadIdx.x;
  if (tid < 88) {
    float s = 0.f;
    for (int q = 0; q < 64; ++q) s += ghist[q * 88 + tid];  // coalesced across tid
    hr[tid] = s;
  }
  if (tid >= 128 && tid < 192) {
    int l = tid - 128;
    float ce = waveSum(ceSlots[l]);
    float fo = waveSum(focalSlots[l]);
    if (l == 0) { scf[0] = ce; scf[1] = fo; }
  }
  __syncthreads();
  if (tid == 0) {
    // Running sums straight from LDS (low-VGPR finale).
    float totAU = 0.f, totIU = 0.f;
    for (int j = 0; j < 22; ++j) { totAU += hr[22 + j]; totIU += hr[66 + j]; }
    float n_ac = 0.f, n_ic = 0.f, n_au = totAU, n_iu = totIU;
    float auc = 0.f, prev = 0.f;
    for (int k = 0; k < 21; ++k) {
      n_ac += hr[k]; n_ic += hr[44 + k];
      n_au -= hr[22 + k]; n_iu -= hr[66 + k];
      float avu = (n_ac + n_iu) / (n_ac + n_au + n_ic + n_iu + 1e-10f);
      if (k > 0) auc += (avu + prev) * 0.5f * 0.05f;
      prev = avu;
    }
    out[0] = -logf(fmaxf(auc, 1e-10f)) + scf[1] * invN;
    out[1] = scf[0] * invN;
  }
}

extern "C" void kernel_launch(void* const* d_in, const int* in_sizes, int n_in,
                              void* d_out, int out_size, void* d_ws, size_t ws_size,
                              hipStream_t stream) {
  const float* probs = (const float*)d_in[0];
  const float* y = (const float*)d_in[1];
  float* out = (float*)d_out;
  const int N = in_sizes[0] / C;

  // ws layout (floats): [0,64) uminInv slots, [64,128) umax slots,
  // [128,192) ce slots, [192,256) focal slots, [256,5888) ghist[64][88],
  // [5888, 5888+N) us
  float* wsf = (float*)d_ws;
  unsigned* uminInvSlots = (unsigned*)wsf;
  unsigned* umaxSlots = (unsigned*)(wsf + 64);
  float* ceSlots = wsf + 128;
  float* focalSlots = wsf + 192;
  float* ghist = wsf + 256;
  float* us = wsf + 5888;

  hipMemsetAsync(d_ws, 0, 5888 * sizeof(float), stream);  // accumulators -> 0

  const int nchunks = N / CHUNK_ROWS;  // 4194304/128 = 32768
  float invN = 1.0f / (float)N;

  pass1<<<4096, 128, 0, stream>>>((const float4*)probs, (const float4*)y,
                                  (float2*)us, uminInvSlots, umaxSlots,
                                  ceSlots, focalSlots, nchunks);
  pass2<<<1024, 256, 0, stream>>>((const float4*)us, N / 4, uminInvSlots,
                                  umaxSlots, ghist);
  pass3<<<1, 256, 0, stream>>>(ghist, ceSlots, focalSlots, out, invN);
}